// Round 7
// baseline (1649.406 us; speedup 1.0000x reference)
//
#include <hip/hip_runtime.h>
#include <hip/hip_fp16.h>

#define ITERS 100
#define AGENT __HIP_MEMORY_SCOPE_AGENT

// 8-byte message: fp32 value + iteration tag, ONE relaxed agent-scope atomic.
// Tag==it+1 validates the value (0xAA poison never matches a tag 1..100).
// Poll-is-read: observing the tag IS the data delivery.
//
// SLAB DECOMPOSITION (round-6 design, resubmitted with lower GEMM register
// pressure after an infra-failed bench). Block b owns rows 8b..8b+7 AND cols
// 8b..8b+7 of K (two 8x2048 fp16 slabs in LDS, built by two skinny GEMMs).
//  * u-phase: 8-row matvec fully local (64 MAC/thread), post 8 u-values,
//    all-gather the 2048-vector (8 contiguous slots/thread = one 64B line
//    per poll round -- the round-5-validated poll shape, 1 detect event).
//  * all scalar side-channels eliminated: every block holds full u and v;
//    sums / uN / vN computed locally, bitwise-identical everywhere.
//  * parity safety (2 buffers): block posts iter-it only after gathering all
//    iter-(it-1) messages -> transitively, every block finished reading the
//    iter-(it-2) values being overwritten.
union PK { unsigned long long u; struct { float v; unsigned tag; } s; };

// ws layout (8-byte units): umsg[2][2048], vmsg[2][2048]
__device__ __forceinline__ float wave_sum(float p) {
    p += __shfl_xor(p, 1, 64);
    p += __shfl_xor(p, 2, 64);
    p += __shfl_xor(p, 4, 64);
    p += __shfl_xor(p, 8, 64);
    p += __shfl_xor(p, 16, 64);
    p += __shfl_xor(p, 32, 64);
    return p;
}

__global__ void __launch_bounds__(256, 1)
sinkhorn_fused(const float* __restrict__ Q, const float* __restrict__ R,
               const float* __restrict__ zp, float* __restrict__ out,
               unsigned long long* __restrict__ ws)
{
    // 64.5 KiB LDS: row slab + col slab + small reduction scratch.
    __shared__ __align__(16) char smem[66048];
    char* KrowB = smem;                     // fp16 [8][2048]: K[8b+r][j]
    char* KcolB = smem + 32768;             // fp16 [8][2048]: K[i][8b+c] (col-major)
    float* red  = (float*)(smem + 65536);   // [4][8]  per-wave row/col partials
    float* red2 = (float*)(smem + 65664);   // [4]     per-wave vector-sum partials
    float* uown = (float*)(smem + 65680);   // [8]     u of own rows (epilogue)
    float* vown = (float*)(smem + 65712);   // [8]     v of own cols (epilogue)

    const int t = threadIdx.x;
    const int b = blockIdx.x;
    const int l = t & 63, w = t >> 6;
    const float E = expf(zp[0] * 10.0f);

    // ---------------- skinny GEMM 1: row slab S[8][2048], K=512 ----------------
    // acc[r][c] = score(8b+r, 8t+c). Q-slab loads are wave-uniform; R rows
    // stream through L2 (4 MB, fits one XCD L2 shared by its 32 blocks).
    // Register budget: 8 r4 + 1 q4 + acc[8][8] live -> no spill.
    {
        float acc[8][8];
#pragma unroll
        for (int r = 0; r < 8; r++)
#pragma unroll
            for (int c = 0; c < 8; c++) acc[r][c] = 0.f;
        const float* Qs = Q + (size_t)(8 * b) * 512;
        const float* Rt = R + (size_t)(8 * t) * 512;
        for (int k = 0; k < 512; k += 4) {
            float4 r4[8];
#pragma unroll
            for (int c = 0; c < 8; c++) r4[c] = *(const float4*)(Rt + c * 512 + k);
#pragma unroll
            for (int r = 0; r < 8; r++) {
                float4 q = *(const float4*)(Qs + r * 512 + k);
#pragma unroll
                for (int c = 0; c < 8; c++)
                    acc[r][c] = fmaf(q.x, r4[c].x, fmaf(q.y, r4[c].y,
                                fmaf(q.z, r4[c].z, fmaf(q.w, r4[c].w, acc[r][c]))));
            }
        }
#pragma unroll
        for (int r = 0; r < 8; r++) {       // K0 = exp(score*10) -> fp16
            unsigned short h[8];
#pragma unroll
            for (int c = 0; c < 8; c++)
                h[c] = __half_as_ushort(__float2half(expf(acc[r][c] * 10.0f)));
            uint4 pk;
            pk.x = h[0] | ((unsigned)h[1] << 16); pk.y = h[2] | ((unsigned)h[3] << 16);
            pk.z = h[4] | ((unsigned)h[5] << 16); pk.w = h[6] | ((unsigned)h[7] << 16);
            *(uint4*)(KrowB + r * 4096 + t * 16) = pk;
        }
    }
    // ---------------- skinny GEMM 2: col slab S[:,8b..8b+7], roles swapped ----------------
    {
        float acc[8][8];
#pragma unroll
        for (int c = 0; c < 8; c++)
#pragma unroll
            for (int i = 0; i < 8; i++) acc[c][i] = 0.f;
        const float* Rs = R + (size_t)(8 * b) * 512;
        const float* Qt = Q + (size_t)(8 * t) * 512;
        for (int k = 0; k < 512; k += 4) {
            float4 q4[8];
#pragma unroll
            for (int i = 0; i < 8; i++) q4[i] = *(const float4*)(Qt + i * 512 + k);
#pragma unroll
            for (int c = 0; c < 8; c++) {
                float4 r = *(const float4*)(Rs + c * 512 + k);
#pragma unroll
                for (int i = 0; i < 8; i++)
                    acc[c][i] = fmaf(r.x, q4[i].x, fmaf(r.y, q4[i].y,
                                fmaf(r.z, q4[i].z, fmaf(r.w, q4[i].w, acc[c][i]))));
            }
        }
#pragma unroll
        for (int c = 0; c < 8; c++) {
            unsigned short h[8];
#pragma unroll
            for (int i = 0; i < 8; i++)
                h[i] = __half_as_ushort(__float2half(expf(acc[c][i] * 10.0f)));
            uint4 pk;
            pk.x = h[0] | ((unsigned)h[1] << 16); pk.y = h[2] | ((unsigned)h[3] << 16);
            pk.z = h[4] | ((unsigned)h[5] << 16); pk.w = h[6] | ((unsigned)h[7] << 16);
            *(uint4*)(KcolB + c * 4096 + t * 16) = pk;
        }
    }

    unsigned long long* umsg = ws;
    unsigned long long* vmsg = ws + 2 * 2048;

    // Per-thread state: v/u values for global indices 8t..8t+7.
    float v[8], ug[8];
#pragma unroll
    for (int c = 0; c < 8; c++) v[c] = 1.0f;
    float vN = 1.0f, uN = 0.0f, sv = 2048.0f, su = 0.0f;
    __syncthreads();                        // slabs ready

    // ---------------- 100 Sinkhorn iterations ----------------
    for (int it = 0; it < ITERS; it++) {
        const unsigned tagw = (unsigned)(it + 1);
        const int buf = it & 1;

        // ======== u-phase ========
        {
            float p[8];
#pragma unroll
            for (int r = 0; r < 8; r++) p[r] = 0.f;
#pragma unroll
            for (int r = 0; r < 8; r++) {   // partial over cols 8t..8t+7
                uint4 kq = *(const uint4*)(KrowB + r * 4096 + t * 16);
                const __half2* h2 = (const __half2*)&kq;
                float2 f;
                f = __half22float2(h2[0]); p[r] = fmaf(f.x, v[0], fmaf(f.y, v[1], p[r]));
                f = __half22float2(h2[1]); p[r] = fmaf(f.x, v[2], fmaf(f.y, v[3], p[r]));
                f = __half22float2(h2[2]); p[r] = fmaf(f.x, v[4], fmaf(f.y, v[5], p[r]));
                f = __half22float2(h2[3]); p[r] = fmaf(f.x, v[6], fmaf(f.y, v[7], p[r]));
            }
#pragma unroll
            for (int r = 0; r < 8; r++) p[r] = wave_sum(p[r]);
            if (l == 0) {
#pragma unroll
                for (int r = 0; r < 8; r++) red[w * 8 + r] = p[r];
            }
            uN = 1.0f / (E * (sv + vN));    // local: full v sum known
            __syncthreads();
            if (t < 8) {                    // finalize + post own 8 u's
                float rsum = red[t] + red[8 + t] + red[16 + t] + red[24 + t];
                float uu = 1.0f / (rsum + E * vN);
                uown[t] = uu;
                PK pk; pk.s.v = uu; pk.s.tag = tagw;
                __hip_atomic_store(umsg + (size_t)buf * 2048 + 8 * b + t, pk.u,
                                   __ATOMIC_RELAXED, AGENT);
            }
            // all-gather: thread t polls slots 8t..8t+7 (one 64B line / round)
            unsigned long long* gb = umsg + (size_t)buf * 2048 + 8 * t;
            for (;;) {
                PK m[8];
#pragma unroll
                for (int s = 0; s < 8; s++)
                    m[s].u = __hip_atomic_load(gb + s, __ATOMIC_RELAXED, AGENT);
                int cnt = 0;
#pragma unroll
                for (int s = 0; s < 8; s++) cnt += (m[s].s.tag == tagw);
                if (cnt == 8) {
#pragma unroll
                    for (int s = 0; s < 8; s++) ug[s] = m[s].s.v;
                    break;
                }
                __builtin_amdgcn_s_sleep(1);
            }
            float sp = ug[0] + ug[1] + ug[2] + ug[3] + ug[4] + ug[5] + ug[6] + ug[7];
            sp = wave_sum(sp);
            if (l == 0) red2[w] = sp;
            __syncthreads();
            su = red2[0] + red2[1] + red2[2] + red2[3];   // full u sum
        }

        // ======== v-phase ========
        {
            float p[8];
#pragma unroll
            for (int c = 0; c < 8; c++) p[c] = 0.f;
#pragma unroll
            for (int c = 0; c < 8; c++) {   // partial over rows 8t..8t+7
                uint4 kq = *(const uint4*)(KcolB + c * 4096 + t * 16);
                const __half2* h2 = (const __half2*)&kq;
                float2 f;
                f = __half22float2(h2[0]); p[c] = fmaf(f.x, ug[0], fmaf(f.y, ug[1], p[c]));
                f = __half22float2(h2[1]); p[c] = fmaf(f.x, ug[2], fmaf(f.y, ug[3], p[c]));
                f = __half22float2(h2[2]); p[c] = fmaf(f.x, ug[4], fmaf(f.y, ug[5], p[c]));
                f = __half22float2(h2[3]); p[c] = fmaf(f.x, ug[6], fmaf(f.y, ug[7], p[c]));
            }
#pragma unroll
            for (int c = 0; c < 8; c++) p[c] = wave_sum(p[c]);
            if (l == 0) {
#pragma unroll
                for (int c = 0; c < 8; c++) red[w * 8 + c] = p[c];
            }
            const float vNn = 1.0f / (E * (su + uN));
            __syncthreads();
            if (t < 8) {
                float csum = red[t] + red[8 + t] + red[16 + t] + red[24 + t];
                float vv = 1.0f / (csum + E * uN);
                vown[t] = vv;
                PK pk; pk.s.v = vv; pk.s.tag = tagw;
                __hip_atomic_store(vmsg + (size_t)buf * 2048 + 8 * b + t, pk.u,
                                   __ATOMIC_RELAXED, AGENT);
            }
            unsigned long long* gb = vmsg + (size_t)buf * 2048 + 8 * t;
            for (;;) {
                PK m[8];
#pragma unroll
                for (int s = 0; s < 8; s++)
                    m[s].u = __hip_atomic_load(gb + s, __ATOMIC_RELAXED, AGENT);
                int cnt = 0;
#pragma unroll
                for (int s = 0; s < 8; s++) cnt += (m[s].s.tag == tagw);
                if (cnt == 8) {
#pragma unroll
                    for (int s = 0; s < 8; s++) v[s] = m[s].s.v;
                    break;
                }
                __builtin_amdgcn_s_sleep(1);
            }
            float sp = v[0] + v[1] + v[2] + v[3] + v[4] + v[5] + v[6] + v[7];
            sp = wave_sum(sp);
            if (l == 0) red2[w] = sp;
            __syncthreads();
            sv = red2[0] + red2[1] + red2[2] + red2[3];   // full v sum
            vN = vNn;
        }
    }

    // ---------------- epilogue: P = u_i K0 v_j (rows 8b..8b+7) ----------------
    float* P  = out;                        // [2048][2048]
    float* PA = out + (size_t)2048 * 2048;  // [2049][2049]
#pragma unroll
    for (int r = 0; r < 8; r++) {
        float ur = uown[r];
        uint4 kq = *(const uint4*)(KrowB + r * 4096 + t * 16);
        const __half2* h2 = (const __half2*)&kq;
        float pv[8];
        float2 f;
        f = __half22float2(h2[0]); pv[0] = ur * f.x * v[0]; pv[1] = ur * f.y * v[1];
        f = __half22float2(h2[1]); pv[2] = ur * f.x * v[2]; pv[3] = ur * f.y * v[3];
        f = __half22float2(h2[2]); pv[4] = ur * f.x * v[4]; pv[5] = ur * f.y * v[5];
        f = __half22float2(h2[3]); pv[6] = ur * f.x * v[6]; pv[7] = ur * f.y * v[7];
        size_t gi = (size_t)(8 * b + r);
        *(float4*)&P[gi * 2048 + 8 * t]     = make_float4(pv[0], pv[1], pv[2], pv[3]);
        *(float4*)&P[gi * 2048 + 8 * t + 4] = make_float4(pv[4], pv[5], pv[6], pv[7]);
        float* pa = &PA[gi * 2049 + 8 * t];
#pragma unroll
        for (int c = 0; c < 8; c++) pa[c] = pv[c];
        if (t == 0) PA[gi * 2049 + 2048] = ur * E * vN;          // last col
    }
    if (t < 8)                                                    // last row (own cols)
        PA[(size_t)2048 * 2049 + 8 * b + t] = uN * E * vown[t];
    if (b == 255 && t == 0)                                       // corner
        PA[(size_t)2048 * 2049 + 2048] = uN * E * vN;
}

extern "C" void kernel_launch(void* const* d_in, const int* in_sizes, int n_in,
                              void* d_out, int out_size, void* d_ws, size_t ws_size,
                              hipStream_t stream)
{
    (void)in_sizes; (void)n_in; (void)out_size; (void)ws_size;
    const float* Q  = (const float*)d_in[0];
    const float* R  = (const float*)d_in[1];
    const float* zp = (const float*)d_in[2];
    float* out = (float*)d_out;
    unsigned long long* ws = (unsigned long long*)d_ws;
    void* args[] = { (void*)&Q, (void*)&R, (void*)&zp, (void*)&out, (void*)&ws };
    // 256 blocks == 256 CUs, 1 block/CU -> co-resident for spin-wait.
    // ws use: 64 KiB of tagged message slots; tags self-validate vs 0xAA poison.
    hipLaunchCooperativeKernel((const void*)sinkhorn_fused, dim3(256), dim3(256),
                               args, 0, stream);
}

// Round 8
// 1574.242 us; speedup vs baseline: 1.0477x; 1.0477x over previous
//
#include <hip/hip_runtime.h>
#include <hip/hip_fp16.h>

#define ITERS 100
#define AGENT __HIP_MEMORY_SCOPE_AGENT

// 8-byte message: fp32 value + iteration tag, ONE relaxed agent-scope atomic.
// Tag==it+1 validates the value (0xAA poison never matches a tag 1..100).
// Poll-is-read: observing the tag IS the data delivery.
//
// Round-8: SLAB DECOMPOSITION + 16-WAY REPLICATED MESSAGE BOARD.
// Block b owns rows 8b..8b+7 AND cols 8b..8b+7 of K (two 8x2048 fp16 slabs
// in LDS). Per phase: tiny local matvec (64 MAC/thread), 8 finalizer threads
// broadcast the block's 8 values to 16 replicated boards (128 fire-and-forget
// stores), then ONE detect event: thread t polls its own 64B line of its
// group's board. 16 blocks/group x 8 threads = 128 pollers/line spread over
// 512 KB -- round-5's proven contention shape (round-7 showed 256 pollers on
// a 16 KB region doubles the poll round: MALL serializes same-line service).
// All scalar side-channels eliminated (full u,v held locally -> sums local).
// Parity safety (2 buffers): posting u[it+2] requires having gathered all
// v[it+1], which transitively proves every block completed its u[it] gather.
union PK { unsigned long long u; struct { float v; unsigned tag; } s; };

// ws layout (8-byte units): umsg[2][16][2048], vmsg[2][16][2048]  (1 MiB total)
#define GCOPY 2048
#define UMSGN (2 * 16 * GCOPY)

__device__ __forceinline__ float wave_sum(float p) {
    p += __shfl_xor(p, 1, 64);
    p += __shfl_xor(p, 2, 64);
    p += __shfl_xor(p, 4, 64);
    p += __shfl_xor(p, 8, 64);
    p += __shfl_xor(p, 16, 64);
    p += __shfl_xor(p, 32, 64);
    return p;
}

__global__ void __launch_bounds__(256, 1)
sinkhorn_fused(const float* __restrict__ Q, const float* __restrict__ R,
               const float* __restrict__ zp, float* __restrict__ out,
               unsigned long long* __restrict__ ws)
{
    // 64.5 KiB LDS: row slab + col slab + small reduction scratch.
    __shared__ __align__(16) char smem[66048];
    char* KrowB = smem;                     // fp16 [8][2048]: K[8b+r][j]
    char* KcolB = smem + 32768;             // fp16 [8][2048]: K[i][8b+c] (col-major)
    float* red  = (float*)(smem + 65536);   // [4][8]  per-wave row/col partials
    float* red2 = (float*)(smem + 65664);   // [4]     per-wave vector-sum partials
    float* uown = (float*)(smem + 65680);   // [8]     u of own rows (epilogue)
    float* vown = (float*)(smem + 65712);   // [8]     v of own cols (epilogue)

    const int t = threadIdx.x;
    const int b = blockIdx.x;
    const int l = t & 63, w = t >> 6;
    const int g = b & 15;                   // consumer group (16 blocks each)
    const float E = expf(zp[0] * 10.0f);

    // ---------------- skinny GEMM 1: row slab S[8][2048], K=512 ----------------
    {
        float acc[8][8];
#pragma unroll
        for (int r = 0; r < 8; r++)
#pragma unroll
            for (int c = 0; c < 8; c++) acc[r][c] = 0.f;
        const float* Qs = Q + (size_t)(8 * b) * 512;
        const float* Rt = R + (size_t)(8 * t) * 512;
        for (int k = 0; k < 512; k += 4) {
            float4 r4[8];
#pragma unroll
            for (int c = 0; c < 8; c++) r4[c] = *(const float4*)(Rt + c * 512 + k);
#pragma unroll
            for (int r = 0; r < 8; r++) {
                float4 q = *(const float4*)(Qs + r * 512 + k);
#pragma unroll
                for (int c = 0; c < 8; c++)
                    acc[r][c] = fmaf(q.x, r4[c].x, fmaf(q.y, r4[c].y,
                                fmaf(q.z, r4[c].z, fmaf(q.w, r4[c].w, acc[r][c]))));
            }
        }
#pragma unroll
        for (int r = 0; r < 8; r++) {       // K0 = exp(score*10) -> fp16
            unsigned short h[8];
#pragma unroll
            for (int c = 0; c < 8; c++)
                h[c] = __half_as_ushort(__float2half(expf(acc[r][c] * 10.0f)));
            uint4 pk;
            pk.x = h[0] | ((unsigned)h[1] << 16); pk.y = h[2] | ((unsigned)h[3] << 16);
            pk.z = h[4] | ((unsigned)h[5] << 16); pk.w = h[6] | ((unsigned)h[7] << 16);
            *(uint4*)(KrowB + r * 4096 + t * 16) = pk;
        }
    }
    // ---------------- skinny GEMM 2: col slab S[:,8b..8b+7] ----------------
    {
        float acc[8][8];
#pragma unroll
        for (int c = 0; c < 8; c++)
#pragma unroll
            for (int i = 0; i < 8; i++) acc[c][i] = 0.f;
        const float* Rs = R + (size_t)(8 * b) * 512;
        const float* Qt = Q + (size_t)(8 * t) * 512;
        for (int k = 0; k < 512; k += 4) {
            float4 q4[8];
#pragma unroll
            for (int i = 0; i < 8; i++) q4[i] = *(const float4*)(Qt + i * 512 + k);
#pragma unroll
            for (int c = 0; c < 8; c++) {
                float4 r = *(const float4*)(Rs + c * 512 + k);
#pragma unroll
                for (int i = 0; i < 8; i++)
                    acc[c][i] = fmaf(r.x, q4[i].x, fmaf(r.y, q4[i].y,
                                fmaf(r.z, q4[i].z, fmaf(r.w, q4[i].w, acc[c][i]))));
            }
        }
#pragma unroll
        for (int c = 0; c < 8; c++) {
            unsigned short h[8];
#pragma unroll
            for (int i = 0; i < 8; i++)
                h[i] = __half_as_ushort(__float2half(expf(acc[c][i] * 10.0f)));
            uint4 pk;
            pk.x = h[0] | ((unsigned)h[1] << 16); pk.y = h[2] | ((unsigned)h[3] << 16);
            pk.z = h[4] | ((unsigned)h[5] << 16); pk.w = h[6] | ((unsigned)h[7] << 16);
            *(uint4*)(KcolB + c * 4096 + t * 16) = pk;
        }
    }

    unsigned long long* umsg = ws;
    unsigned long long* vmsg = ws + UMSGN;

    // Per-thread state: v/u values for global indices 8t..8t+7.
    float v[8], ug[8];
#pragma unroll
    for (int c = 0; c < 8; c++) v[c] = 1.0f;
    float vN = 1.0f, uN = 0.0f, sv = 2048.0f, su = 0.0f;
    __syncthreads();                        // slabs ready

    // ---------------- 100 Sinkhorn iterations ----------------
    for (int it = 0; it < ITERS; it++) {
        const unsigned tagw = (unsigned)(it + 1);
        const int buf = it & 1;

        // ======== u-phase ========
        {
            float p[8];
#pragma unroll
            for (int r = 0; r < 8; r++) p[r] = 0.f;
#pragma unroll
            for (int r = 0; r < 8; r++) {   // partial over cols 8t..8t+7
                uint4 kq = *(const uint4*)(KrowB + r * 4096 + t * 16);
                const __half2* h2 = (const __half2*)&kq;
                float2 f;
                f = __half22float2(h2[0]); p[r] = fmaf(f.x, v[0], fmaf(f.y, v[1], p[r]));
                f = __half22float2(h2[1]); p[r] = fmaf(f.x, v[2], fmaf(f.y, v[3], p[r]));
                f = __half22float2(h2[2]); p[r] = fmaf(f.x, v[4], fmaf(f.y, v[5], p[r]));
                f = __half22float2(h2[3]); p[r] = fmaf(f.x, v[6], fmaf(f.y, v[7], p[r]));
            }
#pragma unroll
            for (int r = 0; r < 8; r++) p[r] = wave_sum(p[r]);
            if (l == 0) {
#pragma unroll
                for (int r = 0; r < 8; r++) red[w * 8 + r] = p[r];
            }
            uN = 1.0f / (E * (sv + vN));    // local: full v sum known
            __syncthreads();
            if (t < 8) {                    // finalize + broadcast to 16 boards
                float rsum = red[t] + red[8 + t] + red[16 + t] + red[24 + t];
                float uu = 1.0f / (rsum + E * vN);
                uown[t] = uu;
                PK pk; pk.s.v = uu; pk.s.tag = tagw;
                unsigned long long* ub = umsg + (size_t)buf * 16 * GCOPY + 8 * b + t;
#pragma unroll
                for (int gg = 0; gg < 16; gg++)
                    __hip_atomic_store(ub + gg * GCOPY, pk.u, __ATOMIC_RELAXED, AGENT);
            }
            // all-gather from OWN group's board: thread t polls one 64B line
            unsigned long long* gb = umsg + (size_t)(buf * 16 + g) * GCOPY + 8 * t;
            for (;;) {
                PK m[8];
#pragma unroll
                for (int s = 0; s < 8; s++)
                    m[s].u = __hip_atomic_load(gb + s, __ATOMIC_RELAXED, AGENT);
                int cnt = 0;
#pragma unroll
                for (int s = 0; s < 8; s++) cnt += (m[s].s.tag == tagw);
                if (cnt == 8) {
#pragma unroll
                    for (int s = 0; s < 8; s++) ug[s] = m[s].s.v;
                    break;
                }
                __builtin_amdgcn_s_sleep(1);
            }
            float sp = ug[0] + ug[1] + ug[2] + ug[3] + ug[4] + ug[5] + ug[6] + ug[7];
            sp = wave_sum(sp);
            if (l == 0) red2[w] = sp;
            __syncthreads();
            su = red2[0] + red2[1] + red2[2] + red2[3];   // full u sum
        }

        // ======== v-phase ========
        {
            float p[8];
#pragma unroll
            for (int c = 0; c < 8; c++) p[c] = 0.f;
#pragma unroll
            for (int c = 0; c < 8; c++) {   // partial over rows 8t..8t+7
                uint4 kq = *(const uint4*)(KcolB + c * 4096 + t * 16);
                const __half2* h2 = (const __half2*)&kq;
                float2 f;
                f = __half22float2(h2[0]); p[c] = fmaf(f.x, ug[0], fmaf(f.y, ug[1], p[c]));
                f = __half22float2(h2[1]); p[c] = fmaf(f.x, ug[2], fmaf(f.y, ug[3], p[c]));
                f = __half22float2(h2[2]); p[c] = fmaf(f.x, ug[4], fmaf(f.y, ug[5], p[c]));
                f = __half22float2(h2[3]); p[c] = fmaf(f.x, ug[6], fmaf(f.y, ug[7], p[c]));
            }
#pragma unroll
            for (int c = 0; c < 8; c++) p[c] = wave_sum(p[c]);
            if (l == 0) {
#pragma unroll
                for (int c = 0; c < 8; c++) red[w * 8 + c] = p[c];
            }
            const float vNn = 1.0f / (E * (su + uN));
            __syncthreads();
            if (t < 8) {
                float csum = red[t] + red[8 + t] + red[16 + t] + red[24 + t];
                float vv = 1.0f / (csum + E * uN);
                vown[t] = vv;
                PK pk; pk.s.v = vv; pk.s.tag = tagw;
                unsigned long long* vb = vmsg + (size_t)buf * 16 * GCOPY + 8 * b + t;
#pragma unroll
                for (int gg = 0; gg < 16; gg++)
                    __hip_atomic_store(vb + gg * GCOPY, pk.u, __ATOMIC_RELAXED, AGENT);
            }
            unsigned long long* gb = vmsg + (size_t)(buf * 16 + g) * GCOPY + 8 * t;
            for (;;) {
                PK m[8];
#pragma unroll
                for (int s = 0; s < 8; s++)
                    m[s].u = __hip_atomic_load(gb + s, __ATOMIC_RELAXED, AGENT);
                int cnt = 0;
#pragma unroll
                for (int s = 0; s < 8; s++) cnt += (m[s].s.tag == tagw);
                if (cnt == 8) {
#pragma unroll
                    for (int s = 0; s < 8; s++) v[s] = m[s].s.v;
                    break;
                }
                __builtin_amdgcn_s_sleep(1);
            }
            float sp = v[0] + v[1] + v[2] + v[3] + v[4] + v[5] + v[6] + v[7];
            sp = wave_sum(sp);
            if (l == 0) red2[w] = sp;
            __syncthreads();
            sv = red2[0] + red2[1] + red2[2] + red2[3];   // full v sum
            vN = vNn;
        }
    }

    // ---------------- epilogue: P = u_i K0 v_j (rows 8b..8b+7) ----------------
    float* P  = out;                        // [2048][2048]
    float* PA = out + (size_t)2048 * 2048;  // [2049][2049]
#pragma unroll
    for (int r = 0; r < 8; r++) {
        float ur = uown[r];
        uint4 kq = *(const uint4*)(KrowB + r * 4096 + t * 16);
        const __half2* h2 = (const __half2*)&kq;
        float pv[8];
        float2 f;
        f = __half22float2(h2[0]); pv[0] = ur * f.x * v[0]; pv[1] = ur * f.y * v[1];
        f = __half22float2(h2[1]); pv[2] = ur * f.x * v[2]; pv[3] = ur * f.y * v[3];
        f = __half22float2(h2[2]); pv[4] = ur * f.x * v[4]; pv[5] = ur * f.y * v[5];
        f = __half22float2(h2[3]); pv[6] = ur * f.x * v[6]; pv[7] = ur * f.y * v[7];
        size_t gi = (size_t)(8 * b + r);
        *(float4*)&P[gi * 2048 + 8 * t]     = make_float4(pv[0], pv[1], pv[2], pv[3]);
        *(float4*)&P[gi * 2048 + 8 * t + 4] = make_float4(pv[4], pv[5], pv[6], pv[7]);
        float* pa = &PA[gi * 2049 + 8 * t];
#pragma unroll
        for (int c = 0; c < 8; c++) pa[c] = pv[c];
        if (t == 0) PA[gi * 2049 + 2048] = ur * E * vN;          // last col
    }
    if (t < 8)                                                    // last row (own cols)
        PA[(size_t)2048 * 2049 + 8 * b + t] = uN * E * vown[t];
    if (b == 255 && t == 0)                                       // corner
        PA[(size_t)2048 * 2049 + 2048] = uN * E * vN;
}

extern "C" void kernel_launch(void* const* d_in, const int* in_sizes, int n_in,
                              void* d_out, int out_size, void* d_ws, size_t ws_size,
                              hipStream_t stream)
{
    (void)in_sizes; (void)n_in; (void)out_size; (void)ws_size;
    const float* Q  = (const float*)d_in[0];
    const float* R  = (const float*)d_in[1];
    const float* zp = (const float*)d_in[2];
    float* out = (float*)d_out;
    unsigned long long* ws = (unsigned long long*)d_ws;
    void* args[] = { (void*)&Q, (void*)&R, (void*)&zp, (void*)&out, (void*)&ws };
    // 256 blocks == 256 CUs, 1 block/CU -> co-resident for spin-wait.
    // ws use: 1 MiB of tagged message slots; tags self-validate vs 0xAA poison.
    hipLaunchCooperativeKernel((const void*)sinkhorn_fused, dim3(256), dim3(256),
                               args, 0, stream);
}

// Round 9
// 1516.611 us; speedup vs baseline: 1.0876x; 1.0380x over previous
//
#include <hip/hip_runtime.h>
#include <hip/hip_fp16.h>

#define ITERS 100
#define AGENT __HIP_MEMORY_SCOPE_AGENT

// Round-9: r5's winning 16x16 tile topology (group-local sync only -- the
// r7/r8 slab all-gather was a ~5us grid barrier per phase, abandoned), with
// the message protocol replaced by SINGLE-WORD f64 ATOMIC ACCUMULATORS:
//   producer: atomicAdd(cell, partial + 2^32)   (one relaxed agent-scope RMW)
//   consumer: poll ONE 8-byte word; bits >= f64(2^36) <=> all 16 partials in;
//             sum = value - 2^36. Value and arrival-count share the word, so
//             poll-is-read still holds and no consumer-side re-sum is needed.
// Per-phase dedicated accumulators (zeroed once by hipMemsetAsync at launch):
// no reuse -> no zeroing protocol -> no tags -> no parity hazards. Liveness
// rests only on "relaxed agent atomics become visible" (proven r0-r8).
// Counter-bias numerics: ulp(2^36)=1.5e-5 absolute on sums, ~1e-9 relative;
// far below the fp16-K quantization floor (absmax 1.53e-5 in all rounds).
//
// ws layout (f64 words, stride-2 = 16B cells to spread MALL atomic traffic):
//   uacc[100][2048][2]  row sums per u-phase
//   vacc[100][2048][2]  col sums per v-phase
//   utot[100][16][2]    16 replicated copies of sum(u) per iteration
//   vtot[100][16][2]    16 replicated copies of sum(v), consumed next iter
#define UACC_OFF 0
#define VACC_OFF ((size_t)ITERS * 2048 * 2)
#define UTOT_OFF (2 * VACC_OFF)
#define VTOT_OFF (UTOT_OFF + (size_t)ITERS * 16 * 2)
#define WS_F64   (VTOT_OFF + (size_t)ITERS * 16 * 2)

__device__ __forceinline__ float wave_sum(float p) {
    p += __shfl_xor(p, 1, 64);
    p += __shfl_xor(p, 2, 64);
    p += __shfl_xor(p, 4, 64);
    p += __shfl_xor(p, 8, 64);
    p += __shfl_xor(p, 16, 64);
    p += __shfl_xor(p, 32, 64);
    return p;
}

__device__ __forceinline__ void acc_add(double* cell, float val) {
    __hip_atomic_fetch_add(cell, (double)val + 4294967296.0,
                           __ATOMIC_RELAXED, AGENT);
}
__device__ __forceinline__ float poll16(const double* cell) {
    const unsigned long long* p = (const unsigned long long*)cell;
    for (;;) {
        unsigned long long x = __hip_atomic_load(p, __ATOMIC_RELAXED, AGENT);
        if (x >= 0x4230000000000000ull)            // f64 bits of 2^36 = 16*2^32
            return (float)(__longlong_as_double(x) - 68719476736.0);
        __builtin_amdgcn_s_sleep(1);
    }
}

__global__ void __launch_bounds__(256, 1)
sinkhorn_fused(const float* __restrict__ Q, const float* __restrict__ R,
               const float* __restrict__ zp, float* __restrict__ out,
               double* __restrict__ acc)
{
    // 64 KiB GEMM staging / fp16 tiles (aliased) + ~1.1 KiB u/v scratch.
    __shared__ __align__(16) char smem[66624];
    float* As = (float*)smem;               // [2][32][128] k-major A slabs
    float* Bs = (float*)(smem + 32768);     // [2][32][128] k-major B slabs
    char*  TrmB = smem;                     // [128 rows][16 chunks of 16B], swizzled
    char*  TcmB = smem + 32768;             // [128 cols][16 chunks of 16B], swizzled
    float* ubuf = (float*)(smem + 65536);   // [128]
    float* vbuf = (float*)(smem + 66048);   // [128]
    float* redU = (float*)(smem + 66560);   // [2]
    float* redV = (float*)(smem + 66568);   // [2]
    float* sc   = (float*)(smem + 66576);   // [0]=sum(v), [1]=sum(u)

    const int t  = threadIdx.x;
    const int b  = blockIdx.x;
    const int bi = b >> 4, bj = b & 15;
    const int tx = t & 15, ty = t >> 4;
    const int l  = t & 63, w  = t >> 6;
    const int gi0 = bi * 128, gj0 = bj * 128;

    // ---------------- phase 1: 128x128 score tile, fp32 GEMM K=512 ----------------
    float a8[8][8];
#pragma unroll
    for (int r = 0; r < 8; r++)
#pragma unroll
        for (int c = 0; c < 8; c++) a8[r][c] = 0.f;

    const int lr = t & 31, lc4 = t >> 5;
    const float* Qb = Q + (size_t)gi0 * 512;
    const float* Rb = R + (size_t)gj0 * 512;

    float4 qa[4], ra[4];
#pragma unroll
    for (int i = 0; i < 4; i++) {
        qa[i] = *(const float4*)(Qb + (size_t)(lr + 32 * i) * 512 + 4 * lc4);
        ra[i] = *(const float4*)(Rb + (size_t)(lr + 32 * i) * 512 + 4 * lc4);
    }
#pragma unroll
    for (int i = 0; i < 4; i++) {
        int row = lr + 32 * i;
        As[(4*lc4+0)*128 + row] = qa[i].x;  As[(4*lc4+1)*128 + row] = qa[i].y;
        As[(4*lc4+2)*128 + row] = qa[i].z;  As[(4*lc4+3)*128 + row] = qa[i].w;
        Bs[(4*lc4+0)*128 + row] = ra[i].x;  Bs[(4*lc4+1)*128 + row] = ra[i].y;
        Bs[(4*lc4+2)*128 + row] = ra[i].z;  Bs[(4*lc4+3)*128 + row] = ra[i].w;
    }
    __syncthreads();

    for (int ks = 0; ks < 16; ks++) {
        if (ks < 15) {
            int k0 = (ks + 1) * 32;
#pragma unroll
            for (int i = 0; i < 4; i++) {
                qa[i] = *(const float4*)(Qb + (size_t)(lr+32*i)*512 + k0 + 4*lc4);
                ra[i] = *(const float4*)(Rb + (size_t)(lr+32*i)*512 + k0 + 4*lc4);
            }
        }
        const float* A = As + (ks & 1) * (32 * 128);
        const float* B = Bs + (ks & 1) * (32 * 128);
#pragma unroll 4
        for (int k = 0; k < 32; k++) {
            float4 a0 = *(const float4*)(A + k*128 + 8*ty);
            float4 a1 = *(const float4*)(A + k*128 + 8*ty + 4);
            float4 b0 = *(const float4*)(B + k*128 + 8*tx);
            float4 b1 = *(const float4*)(B + k*128 + 8*tx + 4);
            float av[8] = {a0.x,a0.y,a0.z,a0.w,a1.x,a1.y,a1.z,a1.w};
            float bv[8] = {b0.x,b0.y,b0.z,b0.w,b1.x,b1.y,b1.z,b1.w};
#pragma unroll
            for (int r = 0; r < 8; r++)
#pragma unroll
                for (int c = 0; c < 8; c++)
                    a8[r][c] = fmaf(av[r], bv[c], a8[r][c]);
        }
        if (ks < 15) {
            __syncthreads();
            float* An = As + ((ks+1) & 1) * (32 * 128);
            float* Bn = Bs + ((ks+1) & 1) * (32 * 128);
#pragma unroll
            for (int i = 0; i < 4; i++) {
                int row = lr + 32 * i;
                An[(4*lc4+0)*128 + row] = qa[i].x;  An[(4*lc4+1)*128 + row] = qa[i].y;
                An[(4*lc4+2)*128 + row] = qa[i].z;  An[(4*lc4+3)*128 + row] = qa[i].w;
                Bn[(4*lc4+0)*128 + row] = ra[i].x;  Bn[(4*lc4+1)*128 + row] = ra[i].y;
                Bn[(4*lc4+2)*128 + row] = ra[i].z;  Bn[(4*lc4+3)*128 + row] = ra[i].w;
            }
            __syncthreads();
        }
    }
    __syncthreads();                        // As/Bs dead; LDS becomes Trm/Tcm

    // ---------------- phase 2: K0 = exp(score*10) -> swizzled fp16 tiles ----------------
    const float E = expf(zp[0] * 10.0f);
#pragma unroll
    for (int r = 0; r < 8; r++)
#pragma unroll
        for (int c = 0; c < 8; c++) a8[r][c] = expf(a8[r][c] * 10.0f);

#pragma unroll
    for (int r = 0; r < 8; r++) {           // row-major tile: one 16B chunk per row
        int rr = 8 * ty + r;
        unsigned short h[8];
#pragma unroll
        for (int c = 0; c < 8; c++) h[c] = __half_as_ushort(__float2half(a8[r][c]));
        uint4 pk;
        pk.x = h[0] | ((unsigned)h[1] << 16); pk.y = h[2] | ((unsigned)h[3] << 16);
        pk.z = h[4] | ((unsigned)h[5] << 16); pk.w = h[6] | ((unsigned)h[7] << 16);
        *(uint4*)(TrmB + rr * 256 + ((tx ^ (rr & 15)) << 4)) = pk;
    }
#pragma unroll
    for (int c = 0; c < 8; c++) {           // col-major tile
        int cc = 8 * tx + c;
        unsigned short h[8];
#pragma unroll
        for (int r = 0; r < 8; r++) h[r] = __half_as_ushort(__float2half(a8[r][c]));
        uint4 pk;
        pk.x = h[0] | ((unsigned)h[1] << 16); pk.y = h[2] | ((unsigned)h[3] << 16);
        pk.z = h[4] | ((unsigned)h[5] << 16); pk.w = h[6] | ((unsigned)h[7] << 16);
        *(uint4*)(TcmB + cc * 256 + ((ty ^ (cc & 15)) << 4)) = pk;
    }

    double* uacc = acc + UACC_OFF;
    double* vacc = acc + VACC_OFF;
    double* utot = acc + UTOT_OFF;
    double* vtot = acc + VTOT_OFF;
    const bool diag = (bi == bj);

    if (t < 128) vbuf[t] = 1.0f;
    float uN = 0.f, vN = 1.0f;
    __syncthreads();                        // tiles + vbuf ready

    // ---------------- phase 3: 100 Sinkhorn iterations ----------------
    for (int it = 0; it < ITERS; it++) {
        // ======== u-phase: r_i = sum_j K[i,j] v_j ========
        {
            if (t < 128) {                  // local 128-col partial, then ONE atomic
                const char* rp = TrmB + t * 256;
                const float4* v4 = (const float4*)vbuf;
                float racc = 0.f;
#pragma unroll
                for (int c = 0; c < 16; c++) {
                    uint4 kq = *(const uint4*)(rp + ((c ^ (t & 15)) << 4));
                    float4 va = v4[2 * c], vb = v4[2 * c + 1];
                    const __half2* h2 = (const __half2*)&kq;
                    float2 f;
                    f = __half22float2(h2[0]); racc = fmaf(f.x, va.x, fmaf(f.y, va.y, racc));
                    f = __half22float2(h2[1]); racc = fmaf(f.x, va.z, fmaf(f.y, va.w, racc));
                    f = __half22float2(h2[2]); racc = fmaf(f.x, vb.x, fmaf(f.y, vb.y, racc));
                    f = __half22float2(h2[3]); racc = fmaf(f.x, vb.z, fmaf(f.y, vb.w, racc));
                }
                acc_add(uacc + ((size_t)it * 2048 + 128 * bi + t) * 2, racc);
            } else if (t == 128) {          // sum(v) of previous iteration
                sc[0] = (it == 0) ? 2048.0f
                                  : poll16(vtot + ((size_t)it * 16 + bi) * 2);
            }
            if (t < 128) {                  // poll own row word: count+value in one
                float rsum = poll16(uacc + ((size_t)it * 2048 + 128 * bi + t) * 2);
                float ui = 1.0f / (rsum + E * vN);
                ubuf[t] = ui;
                float wsm = wave_sum(ui);
                if (l == 0) redU[w] = wsm;
            }
            __syncthreads();                // ubuf, redU, sc[0] ready
            uN = 1.0f / (E * (sc[0] + vN));
            if (diag && t == 128) {         // broadcast sum(u) to 16 copies
                float usum = redU[0] + redU[1];
                double* ub = utot + (size_t)it * 16 * 2;
#pragma unroll
                for (int g = 0; g < 16; g++)
                    __hip_atomic_fetch_add(ub + g * 2, (double)usum + 4294967296.0,
                                           __ATOMIC_RELAXED, AGENT);
            }
        }

        // ======== v-phase: c_j = sum_i K[i,j] u_i ========
        {
            if (t < 128) {
                const char* cp = TcmB + t * 256;
                const float4* u4 = (const float4*)ubuf;
                float cacc = 0.f;
#pragma unroll
                for (int c = 0; c < 16; c++) {
                    uint4 kq = *(const uint4*)(cp + ((c ^ (t & 15)) << 4));
                    float4 ua = u4[2 * c], ub = u4[2 * c + 1];
                    const __half2* h2 = (const __half2*)&kq;
                    float2 f;
                    f = __half22float2(h2[0]); cacc = fmaf(f.x, ua.x, fmaf(f.y, ua.y, cacc));
                    f = __half22float2(h2[1]); cacc = fmaf(f.x, ua.z, fmaf(f.y, ua.w, cacc));
                    f = __half22float2(h2[2]); cacc = fmaf(f.x, ub.x, fmaf(f.y, ub.y, cacc));
                    f = __half22float2(h2[3]); cacc = fmaf(f.x, ub.z, fmaf(f.y, ub.w, cacc));
                }
                acc_add(vacc + ((size_t)it * 2048 + 128 * bj + t) * 2, cacc);
            } else if (t == 128) {          // sum(u) of this iteration
                sc[1] = poll16(utot + ((size_t)it * 16 + bi) * 2);
            }
            if (t < 128) {
                float csum = poll16(vacc + ((size_t)it * 2048 + 128 * bj + t) * 2);
                float vj = 1.0f / (csum + E * uN);
                vbuf[t] = vj;
                float wsm = wave_sum(vj);
                if (l == 0) redV[w] = wsm;
            }
            __syncthreads();                // vbuf, redV, sc[1] ready
            vN = 1.0f / (E * (sc[1] + uN));
            if (diag && t == 128 && it + 1 < ITERS) {
                float vsum = redV[0] + redV[1];
                double* vb = vtot + (size_t)(it + 1) * 16 * 2;
#pragma unroll
                for (int g = 0; g < 16; g++)
                    __hip_atomic_fetch_add(vb + g * 2, (double)vsum + 4294967296.0,
                                           __ATOMIC_RELAXED, AGENT);
            }
        }
    }

    // ---------------- phase 4: epilogue P = u_i K0 v_j ----------------
    float* P  = out;                        // [2048][2048]
    float* PA = out + (size_t)2048 * 2048;  // [2049][2049]
    float2 vv = *(const float2*)&vbuf[2 * l];
#pragma unroll 2
    for (int rr2 = 0; rr2 < 32; rr2++) {
        int i = 32 * w + rr2;
        float ui = ubuf[i];
        const char* rp = TrmB + i * 256;
        int c = l >> 2;                     // logical chunk of col 2l
        __half2 h2 = *(const __half2*)(rp + ((c ^ (i & 15)) << 4) + (l & 3) * 4);
        float2 kf = __half22float2(h2);
        float p0 = ui * kf.x * vv.x;
        float p1 = ui * kf.y * vv.y;
        size_t gi = (size_t)(gi0 + i);
        *(float2*)&P[gi * 2048 + gj0 + 2 * l] = make_float2(p0, p1);
        PA[gi * 2049 + gj0 + 2 * l]     = p0;
        PA[gi * 2049 + gj0 + 2 * l + 1] = p1;
        if (bj == 15 && l == 0) PA[gi * 2049 + 2048] = ui * E * vN;     // last col
    }
    if (bi == 15 && w == 0) {               // last row + corner
        PA[(size_t)2048 * 2049 + gj0 + 2 * l]     = uN * E * vv.x;
        PA[(size_t)2048 * 2049 + gj0 + 2 * l + 1] = uN * E * vv.y;
        if (bj == 15 && l == 0) PA[(size_t)2048 * 2049 + 2048] = uN * E * vN;
    }
}

extern "C" void kernel_launch(void* const* d_in, const int* in_sizes, int n_in,
                              void* d_out, int out_size, void* d_ws, size_t ws_size,
                              hipStream_t stream)
{
    (void)in_sizes; (void)n_in; (void)out_size; (void)ws_size;
    const float* Q  = (const float*)d_in[0];
    const float* R  = (const float*)d_in[1];
    const float* zp = (const float*)d_in[2];
    float* out = (float*)d_out;
    double* acc = (double*)d_ws;
    // Zero the per-phase accumulators (6.6 MB): value+count scheme needs 0,
    // not 0xAA poison. Async on stream -> graph-capture safe.
    hipMemsetAsync(d_ws, 0, WS_F64 * sizeof(double), stream);
    void* args[] = { (void*)&Q, (void*)&R, (void*)&zp, (void*)&out, (void*)&acc };
    // 256 blocks == 256 CUs, 1 block/CU -> co-resident for spin-wait.
    hipLaunchCooperativeKernel((const void*)sinkhorn_fused, dim3(256), dim3(256),
                               args, 0, stream);
}